// Round 2
// baseline (139.100 us; speedup 1.0000x reference)
//
#include <hip/hip_runtime.h>

// Problem constants
#define NB 4
#define NH 16
#define RR 512
#define CC 512
#define EMB 256
#define SD 16   // qkv dim per head
#define MH 16   // mlp hidden

typedef __attribute__((ext_vector_type(8))) short short8;
typedef __attribute__((ext_vector_type(4))) float f32x4;
typedef __attribute__((ext_vector_type(4))) unsigned short ushort4v;

__device__ __forceinline__ float bf2f(unsigned short s) {
  unsigned u = ((unsigned)s) << 16;
  return __builtin_bit_cast(float, u);
}
__device__ __forceinline__ unsigned short f2bf(float f) {
  unsigned u = __builtin_bit_cast(unsigned, f);
  u = u + 0x7FFFu + ((u >> 16) & 1u);   // round-to-nearest-even
  return (unsigned short)(u >> 16);
}

// ---------------------------------------------------------------------------
// Kernel 0: transpose + downcast weights W[e][n] (256x256 fp32) -> WT[n][e] bf16
// grid (3, 256), block 64.
// ---------------------------------------------------------------------------
__global__ __launch_bounds__(64) void transpose_w(
    const float* __restrict__ Wq, const float* __restrict__ Wk,
    const float* __restrict__ Wv, unsigned short* __restrict__ WT) {
  const float* src = (blockIdx.x == 0) ? Wq : (blockIdx.x == 1) ? Wk : Wv;
  unsigned short* dst = WT + blockIdx.x * (EMB * EMB);
  int n = blockIdx.y;
  int e0 = threadIdx.x * 4;
  ushort4v v;
  v.x = f2bf(src[(e0 + 0) * EMB + n]);
  v.y = f2bf(src[(e0 + 1) * EMB + n]);
  v.z = f2bf(src[(e0 + 2) * EMB + n]);
  v.w = f2bf(src[(e0 + 3) * EMB + n]);
  *(ushort4v*)(dst + n * EMB + e0) = v;
}

// ---------------------------------------------------------------------------
// Kernel 1: projections. Computes Y^T tiles:  D[m=n_out_local][n=row_local]
//   A = WT (bf16, 16B/lane), B = X rows (fp32 -> bf16 convert, 32B/lane).
//   mat 0: Q[b,h,r,s] from row_emb; mat 1: K[b,h,c,s]; mat 2: VT[b,h,s,c].
// 6144 wave-tiles -> 1536 blocks x 256 threads. K-loop: 8 steps of K=32.
// ---------------------------------------------------------------------------
__global__ __launch_bounds__(256) void proj_kernel(
    const float* __restrict__ rowe, const float* __restrict__ cole,
    const unsigned short* __restrict__ WT,
    unsigned short* __restrict__ Q, unsigned short* __restrict__ K,
    unsigned short* __restrict__ VT) {
  int tid = threadIdx.x;
  int wid = tid >> 6, lane = tid & 63, l15 = lane & 15, quad = lane >> 4;
  int wt = blockIdx.x * 4 + wid;        // 0..6143
  int mat = wt >> 11;                   // 0=Q 1=K 2=V
  int t = wt & 2047;
  int rt = t >> 4;                      // M-tile 0..127 (rows of X)
  int nt = t & 15;                      // N-tile = head
  const float* X = (mat == 0) ? rowe : cole;
  const unsigned short* Wm = WT + mat * (EMB * EMB);

  const short8* ap = (const short8*)(Wm + (nt * 16 + l15) * EMB + quad * 8);
  const float* xrow = X + (size_t)(rt * 16 + l15) * EMB + quad * 8;
  f32x4 acc = {0.f, 0.f, 0.f, 0.f};
#pragma unroll
  for (int e = 0; e < 8; ++e) {
    short8 af = ap[e * 4];                       // +32 bf16 per k-step
    f32x4 b0 = *(const f32x4*)(xrow + e * 32);
    f32x4 b1 = *(const f32x4*)(xrow + e * 32 + 4);
    short8 bf;
#pragma unroll
    for (int j = 0; j < 4; ++j) {
      ((unsigned short*)&bf)[j]     = f2bf(b0[j]);
      ((unsigned short*)&bf)[j + 4] = f2bf(b1[j]);
    }
    acc = __builtin_amdgcn_mfma_f32_16x16x32_bf16(af, bf, acc, 0, 0, 0);
  }
  // lane (quad, i) holds Y[row = rt*16+l15][n_out = nt*16 + 4*quad + i]
  int row = rt * 16 + l15;
  int b = row >> 9, loc = row & 511;
  if (mat < 2) {
    unsigned short* dst = ((mat == 0) ? Q : K) +
        ((size_t)((b * NH + nt) * 512 + loc) * SD + quad * 4);
    ushort4v pk;
    pk.x = f2bf(acc[0]); pk.y = f2bf(acc[1]); pk.z = f2bf(acc[2]); pk.w = f2bf(acc[3]);
    *(ushort4v*)dst = pk;
  } else {
#pragma unroll
    for (int i = 0; i < 4; ++i)
      VT[(size_t)((b * NH + nt) * SD + quad * 4 + i) * CC + loc] = f2bf(acc[i]);
  }
}

// ---------------------------------------------------------------------------
// Kernel 2: fused mixed-score attention. grid (8 rblocks, 16 h, 4 b) x 256.
// Wave w owns rows r0 = rb*64 + w*16 .. +16. No cross-wave sharing -> no syncs.
// Phase 1: S^T tiles via MFMA (A=K,B=Q, K-dim padded 16->32), per-element MLP
//          (fp32 weights in registers), row-max tracking, bf16 scores to
//          XOR-swizzled LDS (16KB/wave).
// Phase 2: read scores in A-layout, exp2, accumulate l, P·V via MFMA. fp32 out.
// ---------------------------------------------------------------------------
__global__ __launch_bounds__(256) void attn_kernel(
    const unsigned short* __restrict__ Q, const unsigned short* __restrict__ K,
    const unsigned short* __restrict__ VT, const float* __restrict__ cost,
    const float* __restrict__ m1w, const float* __restrict__ m1b,
    const float* __restrict__ m2w, const float* __restrict__ m2b,
    float* __restrict__ out) {
  __shared__ alignas(16) unsigned short Psh[4][16 * 512];  // 64 KB
  int tid = threadIdx.x;
  int wid = tid >> 6, lane = tid & 63, l15 = lane & 15, quad = lane >> 4;
  int rb = blockIdx.x, h = blockIdx.y, b = blockIdx.z;
  int bh = b * NH + h;
  int r0 = rb * 64 + wid * 16;

  // per-head MLP weights -> registers. /4 (=1/sqrt(16)) folded into wa.
  float wa[MH], wc[MH], wd[MH], we[MH];
#pragma unroll
  for (int m = 0; m < MH; ++m) {
    wa[m] = m1w[(h * 2 + 0) * MH + m] * 0.25f;
    wc[m] = m1w[(h * 2 + 1) * MH + m];
    wd[m] = m1b[h * MH + m];
    we[m] = m2w[h * MH + m];
  }
  float wb2 = m2b[h];

  // loop-invariant Q fragment (B-operand): B[k=s][n=r], zero for s>=16
  short8 qf = {0, 0, 0, 0, 0, 0, 0, 0};
  const unsigned short* Qb = Q + (size_t)bh * RR * SD;
  if (quad < 2) qf = *(const short8*)(Qb + (r0 + l15) * SD + quad * 8);

  const unsigned short* Kb = K + (size_t)bh * CC * SD;
  const float* crow = cost + ((size_t)b * RR + r0 + l15) * CC;
  unsigned short* psrow = &Psh[wid][l15 * 512];

  // ---- phase 1: scores + MLP + max ----
  float mrun = -1e30f;
  for (int ct = 0; ct < CC; ct += 16) {
    short8 kf = {0, 0, 0, 0, 0, 0, 0, 0};
    if (quad < 2) kf = *(const short8*)(Kb + (ct + l15) * SD + quad * 8);
    f32x4 acc = {0.f, 0.f, 0.f, 0.f};
    acc = __builtin_amdgcn_mfma_f32_16x16x32_bf16(kf, qf, acc, 0, 0, 0);
    // lane: r = r0+l15 (fixed), c = ct + 4*quad + i
    int c0 = ct + quad * 4;
    f32x4 cf = *(const f32x4*)(crow + c0);
    ushort4v pk;
#pragma unroll
    for (int i = 0; i < 4; ++i) {
      float x = acc[i];
      float s = wb2;
#pragma unroll
      for (int m = 0; m < MH; ++m) {
        float t1 = fmaf(wc[m], cf[i], wd[m]);
        t1 = fmaf(wa[m], x, t1);
        t1 = fmaxf(t1, 0.f);
        s = fmaf(we[m], t1, s);
      }
      mrun = fmaxf(mrun, s);
      ((unsigned short*)&pk)[i] = f2bf(s);
    }
    int g = ((c0 >> 3) ^ (l15 & 7));          // 16B-granule XOR swizzle
    *(ushort4v*)(psrow + g * 8 + (c0 & 7)) = pk;
  }
  mrun = fmaxf(mrun, __shfl_xor(mrun, 16));
  mrun = fmaxf(mrun, __shfl_xor(mrun, 32));

  // ---- phase 2: exp + l-sum + P·V ----
  const unsigned short* vb = VT + ((size_t)bh * SD + l15) * CC;
  f32x4 o = {0.f, 0.f, 0.f, 0.f};
  float lsum = 0.f;
  const float LOG2E = 1.44269504088896f;
  float mb2 = mrun * LOG2E;
  for (int ct = 0; ct < CC; ct += 32) {
    int c0 = ct + quad * 8;                    // A-frag k-range for this lane
    int g = ((c0 >> 3) ^ (l15 & 7));
    short8 praw = *(const short8*)(psrow + g * 8);
    short8 pf;
#pragma unroll
    for (int j = 0; j < 8; ++j) {
      float x = bf2f((unsigned short)((unsigned short*)&praw)[j]);
      float p = exp2f(fmaf(x, LOG2E, -mb2));
      lsum += p;
      ((unsigned short*)&pf)[j] = (short)f2bf(p);
    }
    short8 vf = *(const short8*)(vb + c0);     // B[k=c][n=s] from VT[b,h,s,c]
    o = __builtin_amdgcn_mfma_f32_16x16x32_bf16(pf, vf, o, 0, 0, 0);
  }
  lsum += __shfl_xor(lsum, 16);
  lsum += __shfl_xor(lsum, 32);

  // lane holds O[r = 4*quad+i][s = l15]; fetch l for those rows from lanes 0..15
#pragma unroll
  for (int i = 0; i < 4; ++i) {
    float li = __shfl(lsum, quad * 4 + i);
    out[((size_t)b * RR + r0 + quad * 4 + i) * (NH * SD) + h * SD + l15] = o[i] / li;
  }
}

// ---------------------------------------------------------------------------
extern "C" void kernel_launch(void* const* d_in, const int* in_sizes, int n_in,
                              void* d_out, int out_size, void* d_ws, size_t ws_size,
                              hipStream_t stream) {
  const float* rowe = (const float*)d_in[0];
  const float* cole = (const float*)d_in[1];
  const float* cost = (const float*)d_in[2];
  const float* Wq   = (const float*)d_in[3];
  const float* Wk   = (const float*)d_in[4];
  const float* Wv   = (const float*)d_in[5];
  const float* m1w  = (const float*)d_in[6];
  const float* m1b  = (const float*)d_in[7];
  const float* m2w  = (const float*)d_in[8];
  const float* m2b  = (const float*)d_in[9];
  float* outp = (float*)d_out;

  // workspace layout (bf16/ushort elements):
  //   Q  [4,16,512,16]  @ 0        (524288)
  //   K  [4,16,512,16]  @ 524288   (524288)
  //   VT [4,16,16,512]  @ 1048576  (524288)
  //   WT [3,256,256]    @ 1572864  (196608)   -> 3538944 bytes total
  unsigned short* ws = (unsigned short*)d_ws;
  unsigned short* Qw  = ws;
  unsigned short* Kw  = ws + 524288;
  unsigned short* VTw = ws + 1048576;
  unsigned short* WTw = ws + 1572864;

  transpose_w<<<dim3(3, 256, 1), 64, 0, stream>>>(Wq, Wk, Wv, WTw);
  proj_kernel<<<dim3(1536, 1, 1), 256, 0, stream>>>(rowe, cole, WTw, Qw, Kw, VTw);
  attn_kernel<<<dim3(8, NH, NB), 256, 0, stream>>>(Qw, Kw, VTw, cost,
                                                   m1w, m1b, m2w, m2b, outp);
}

// Round 3
// 125.733 us; speedup vs baseline: 1.1063x; 1.1063x over previous
//
#include <hip/hip_runtime.h>

// Problem constants
#define NB 4
#define NH 16
#define RR 512
#define CC 512
#define EMB 256
#define SD 16   // qkv dim per head
#define MH 16   // mlp hidden

typedef __attribute__((ext_vector_type(8))) short short8;
typedef __attribute__((ext_vector_type(8))) unsigned short ushort8;
typedef __attribute__((ext_vector_type(4))) float f32x4;
typedef __attribute__((ext_vector_type(4))) unsigned short ushort4v;

__device__ __forceinline__ float bf2f(unsigned short s) {
  unsigned u = ((unsigned)s) << 16;
  return __builtin_bit_cast(float, u);
}
__device__ __forceinline__ unsigned short f2bf(float f) {
  unsigned u = __builtin_bit_cast(unsigned, f);
  u = u + 0x7FFFu + ((u >> 16) & 1u);   // round-to-nearest-even
  return (unsigned short)(u >> 16);
}

// ---------------------------------------------------------------------------
// Kernel 0: W[e][n] (256x256 fp32) -> WT[n][e] bf16.  grid 48 x 256 thr.
// Each thread gathers 16 scattered fp32, writes two 16B packed stores.
// ---------------------------------------------------------------------------
__global__ __launch_bounds__(256) void prep_w(
    const float* __restrict__ Wq, const float* __restrict__ Wk,
    const float* __restrict__ Wv, unsigned short* __restrict__ WT) {
  int bi = blockIdx.x;
  int mat = bi >> 4, ngrp = bi & 15;
  const float* src = (mat == 0) ? Wq : (mat == 1) ? Wk : Wv;
  unsigned short* dst = WT + mat * (EMB * EMB);
  int n = ngrp * 16 + (threadIdx.x >> 4);
  int e0 = (threadIdx.x & 15) * 16;
  ushort8 v0, v1;
#pragma unroll
  for (int j = 0; j < 8; ++j) v0[j] = f2bf(src[(e0 + j) * EMB + n]);
#pragma unroll
  for (int j = 0; j < 8; ++j) v1[j] = f2bf(src[(e0 + 8 + j) * EMB + n]);
  *(ushort8*)(dst + n * EMB + e0) = v0;
  *(ushort8*)(dst + n * EMB + e0 + 8) = v1;
}

// ---------------------------------------------------------------------------
// Kernel 1: projections. Wave converts 16 X-rows to bf16 ONCE, reuses across
// 4 heads (32 MFMA/wave). 1536 waves -> 384 blocks x 256 thr.
//   D[m=n_out_local][n=row_local]: A = WT rows (16B/lane), B = X rows.
//   mat 0: Q[b,h,r,s]; mat 1: K[b,h,c,s]; mat 2: VT[b,h,s,c].
// ---------------------------------------------------------------------------
__global__ __launch_bounds__(256) void proj_kernel(
    const float* __restrict__ rowe, const float* __restrict__ cole,
    const unsigned short* __restrict__ WT,
    unsigned short* __restrict__ Q, unsigned short* __restrict__ K,
    unsigned short* __restrict__ VT) {
  int tid = threadIdx.x;
  int wid = tid >> 6, lane = tid & 63, l15 = lane & 15, quad = lane >> 4;
  int wt = blockIdx.x * 4 + wid;        // 0..1535
  int mat = wt >> 9;                    // 0=Q 1=K 2=V
  int t = wt & 511;
  int rt = t >> 2, ng = t & 3;          // rt 0..127, head group 0..3
  const float* X = (mat == 0) ? rowe : cole;
  const unsigned short* Wm = WT + mat * (EMB * EMB);
  const float* xrow = X + (size_t)(rt * 16 + l15) * EMB + quad * 8;

  short8 xf[8];
#pragma unroll
  for (int e = 0; e < 8; ++e) {
    f32x4 b0 = *(const f32x4*)(xrow + e * 32);
    f32x4 b1 = *(const f32x4*)(xrow + e * 32 + 4);
#pragma unroll
    for (int j = 0; j < 4; ++j) {
      ((unsigned short*)&xf[e])[j]     = f2bf(b0[j]);
      ((unsigned short*)&xf[e])[j + 4] = f2bf(b1[j]);
    }
  }
  int row = rt * 16 + l15;
  int b = row >> 9, loc = row & 511;
#pragma unroll
  for (int hh = 0; hh < 4; ++hh) {
    int nt = ng * 4 + hh;
    const short8* ap = (const short8*)(Wm + (nt * 16 + l15) * EMB + quad * 8);
    f32x4 acc = {0.f, 0.f, 0.f, 0.f};
#pragma unroll
    for (int e = 0; e < 8; ++e)
      acc = __builtin_amdgcn_mfma_f32_16x16x32_bf16(ap[e * 4], xf[e], acc, 0, 0, 0);
    if (mat < 2) {
      ushort4v pk;
      pk.x = f2bf(acc[0]); pk.y = f2bf(acc[1]); pk.z = f2bf(acc[2]); pk.w = f2bf(acc[3]);
      unsigned short* dst = ((mat == 0) ? Q : K) +
          ((size_t)((b * NH + nt) * 512 + loc) * SD + quad * 4);
      *(ushort4v*)dst = pk;
    } else {
#pragma unroll
      for (int i = 0; i < 4; ++i)
        VT[(size_t)((b * NH + nt) * SD + quad * 4 + i) * CC + loc] = f2bf(acc[i]);
    }
  }
}

// ---------------------------------------------------------------------------
// Kernel 2: fused mixed-score attention, c-split flash version.
// grid (16 rb, 16 h, 4 b) x 256 thr. Block = 2 row-tiles x 2 c-halves.
// Wave (rt,ch) does 16 rows x 256 cols: MFMA S^T -> per-score MLP -> bf16
// scores to swizzled LDS (8KB/wave) -> per-row max -> exp/l/P.V MFMA.
// Halves merged flash-style through 3KB LDS + one barrier.
// ---------------------------------------------------------------------------
__global__ __launch_bounds__(256) void attn_kernel(
    const unsigned short* __restrict__ Q, const unsigned short* __restrict__ K,
    const unsigned short* __restrict__ VT, const float* __restrict__ cost,
    const float* __restrict__ m1w, const float* __restrict__ m1b,
    const float* __restrict__ m2w, const float* __restrict__ m2b,
    float* __restrict__ out) {
  __shared__ alignas(16) unsigned short Psh[4][16 * 256];  // 32 KB
  __shared__ float Osh[2][256];                             // ch==1 partial O
  __shared__ float MLsh[2][2][2][16];                       // [rt][ch][m|l][row]
  int tid = threadIdx.x;
  int wid = tid >> 6, lane = tid & 63, l15 = lane & 15, quad = lane >> 4;
  int rt = wid >> 1, ch = wid & 1;
  int rb = blockIdx.x, h = blockIdx.y, b = blockIdx.z;
  int bh = b * NH + h;
  int r0 = rb * 32 + rt * 16;
  int cbase = ch * 256;

  // per-head MLP weights -> registers. /4 (=1/sqrt(16)) folded into wa.
  float wa[MH], wc[MH], wd[MH], we[MH];
#pragma unroll
  for (int m = 0; m < MH; ++m) {
    wa[m] = m1w[(h * 2 + 0) * MH + m] * 0.25f;
    wc[m] = m1w[(h * 2 + 1) * MH + m];
    wd[m] = m1b[h * MH + m];
    we[m] = m2w[h * MH + m];
  }
  float wb2 = m2b[h];

  // loop-invariant Q fragment (B-operand): B[k=s][n=r], zero for s>=16
  short8 qf = {0, 0, 0, 0, 0, 0, 0, 0};
  const unsigned short* Qb = Q + (size_t)bh * RR * SD;
  if (quad < 2) qf = *(const short8*)(Qb + (r0 + l15) * SD + quad * 8);

  const unsigned short* Kb = K + ((size_t)bh * CC + cbase) * SD;
  const float* crow = cost + ((size_t)b * RR + r0 + l15) * CC + cbase;
  unsigned short* psrow = &Psh[wid][l15 * 256];

  // ---- phase 1: scores + MLP + per-row max (prefetched) ----
  float mrun = -1e30f;
  short8 kf_c = {0, 0, 0, 0, 0, 0, 0, 0};
  if (quad < 2) kf_c = *(const short8*)(Kb + l15 * SD + quad * 8);
  f32x4 cf_c = *(const f32x4*)(crow + quad * 4);
#pragma unroll 4
  for (int it = 0; it < 16; ++it) {
    int itn = (it + 1) & 15;                   // wrap: safe, unused on last iter
    short8 kf_n = {0, 0, 0, 0, 0, 0, 0, 0};
    if (quad < 2) kf_n = *(const short8*)(Kb + (itn * 16 + l15) * SD + quad * 8);
    f32x4 cf_n = *(const f32x4*)(crow + itn * 16 + quad * 4);

    f32x4 acc = {0.f, 0.f, 0.f, 0.f};
    acc = __builtin_amdgcn_mfma_f32_16x16x32_bf16(kf_c, qf, acc, 0, 0, 0);
    // lane: r = r0+l15 (fixed), local c = it*16 + 4*quad + i
    int c0 = it * 16 + quad * 4;
    ushort4v pk;
#pragma unroll
    for (int i = 0; i < 4; ++i) {
      float x = acc[i];
      float s = wb2;
#pragma unroll
      for (int m = 0; m < MH; ++m) {
        float t1 = fmaf(wc[m], cf_c[i], wd[m]);
        t1 = fmaf(wa[m], x, t1);
        t1 = fmaxf(t1, 0.f);
        s = fmaf(we[m], t1, s);
      }
      mrun = fmaxf(mrun, s);
      ((unsigned short*)&pk)[i] = f2bf(s);
    }
    int g = ((c0 >> 3) ^ (l15 & 7));          // 16B-granule XOR swizzle
    *(ushort4v*)(psrow + g * 8 + (c0 & 7)) = pk;
    kf_c = kf_n; cf_c = cf_n;
  }
  mrun = fmaxf(mrun, __shfl_xor(mrun, 16));
  mrun = fmaxf(mrun, __shfl_xor(mrun, 32));   // per-row (l15) max

  // ---- phase 2: exp + l-sum + P·V (prefetched) ----
  const unsigned short* vb = VT + ((size_t)bh * SD + l15) * CC + cbase;
  f32x4 o = {0.f, 0.f, 0.f, 0.f};
  float lsum = 0.f;
  const float L2E = 1.44269504088896f;
  float mb2 = mrun * L2E;
  short8 vf_c = *(const short8*)(vb + quad * 8);
  int g0 = ((quad * 8) >> 3) ^ (l15 & 7);
  short8 pr_c = *(const short8*)(psrow + g0 * 8);
#pragma unroll
  for (int it = 0; it < 8; ++it) {
    int itn = (it + 1) & 7;
    short8 vf_n = *(const short8*)(vb + itn * 32 + quad * 8);
    int c0n = itn * 32 + quad * 8;
    int gn = ((c0n >> 3) ^ (l15 & 7));
    short8 pr_n = *(const short8*)(psrow + gn * 8);
    short8 pf;
#pragma unroll
    for (int j = 0; j < 8; ++j) {
      float x = bf2f(((unsigned short*)&pr_c)[j]);
      float p = __builtin_amdgcn_exp2f(fmaf(x, L2E, -mb2));
      lsum += p;
      ((unsigned short*)&pf)[j] = (short)f2bf(p);
    }
    o = __builtin_amdgcn_mfma_f32_16x16x32_bf16(pf, vf_c, o, 0, 0, 0);
    vf_c = vf_n; pr_c = pr_n;
  }
  lsum += __shfl_xor(lsum, 16);
  lsum += __shfl_xor(lsum, 32);               // per-row (l15) partial l

  // ---- merge the two c-halves ----
  if (quad == 0) { MLsh[rt][ch][0][l15] = mrun; MLsh[rt][ch][1][l15] = lsum; }
  if (ch == 1) {
#pragma unroll
    for (int i = 0; i < 4; ++i) Osh[rt][(quad * 4 + i) * 16 + l15] = o[i];
  }
  __syncthreads();
  if (ch == 0) {
#pragma unroll
    for (int i = 0; i < 4; ++i) {
      int r = quad * 4 + i;
      float m0 = MLsh[rt][0][0][r], l0 = MLsh[rt][0][1][r];
      float m1 = MLsh[rt][1][0][r], l1 = MLsh[rt][1][1][r];
      float M = fmaxf(m0, m1);
      float a0 = __builtin_amdgcn_exp2f((m0 - M) * L2E);
      float a1 = __builtin_amdgcn_exp2f((m1 - M) * L2E);
      float l = a0 * l0 + a1 * l1;
      float val = (a0 * o[i] + a1 * Osh[rt][r * 16 + l15]) / l;
      out[((size_t)b * RR + r0 + r) * (NH * SD) + h * SD + l15] = val;
    }
  }
}

// ---------------------------------------------------------------------------
extern "C" void kernel_launch(void* const* d_in, const int* in_sizes, int n_in,
                              void* d_out, int out_size, void* d_ws, size_t ws_size,
                              hipStream_t stream) {
  const float* rowe = (const float*)d_in[0];
  const float* cole = (const float*)d_in[1];
  const float* cost = (const float*)d_in[2];
  const float* Wq   = (const float*)d_in[3];
  const float* Wk   = (const float*)d_in[4];
  const float* Wv   = (const float*)d_in[5];
  const float* m1w  = (const float*)d_in[6];
  const float* m1b  = (const float*)d_in[7];
  const float* m2w  = (const float*)d_in[8];
  const float* m2b  = (const float*)d_in[9];
  float* outp = (float*)d_out;

  // workspace layout (bf16/ushort elements):
  //   Q  [4,16,512,16]  @ 0        (524288)
  //   K  [4,16,512,16]  @ 524288   (524288)
  //   VT [4,16,16,512]  @ 1048576  (524288)
  //   WT [3,256,256]    @ 1572864  (196608)   -> 3538944 bytes total
  unsigned short* ws = (unsigned short*)d_ws;
  unsigned short* Qw  = ws;
  unsigned short* Kw  = ws + 524288;
  unsigned short* VTw = ws + 1048576;
  unsigned short* WTw = ws + 1572864;

  prep_w<<<dim3(48, 1, 1), 256, 0, stream>>>(Wq, Wk, Wv, WTw);
  proj_kernel<<<dim3(384, 1, 1), 256, 0, stream>>>(rowe, cole, WTw, Qw, Kw, VTw);
  attn_kernel<<<dim3(16, NH, NB), 256, 0, stream>>>(Qw, Kw, VTw, cost,
                                                    m1w, m1b, m2w, m2b, outp);
}

// Round 5
// 117.573 us; speedup vs baseline: 1.1831x; 1.0694x over previous
//
#include <hip/hip_runtime.h>

// Problem constants
#define NB 4
#define NH 16
#define RR 512
#define CC 512
#define EMB 256
#define SD 16   // qkv dim per head
#define MH 16   // mlp hidden

typedef __attribute__((ext_vector_type(4))) float f32x4;
typedef __fp16 half2v __attribute__((ext_vector_type(2)));
typedef __fp16 half4v __attribute__((ext_vector_type(4)));
typedef __fp16 half8v __attribute__((ext_vector_type(8)));

union H8 { half8v v; half2v h[4]; __fp16 e[8]; };
union H4 { half4v v; half2v h[2]; __fp16 e[4]; };

// ---------------------------------------------------------------------------
// Kernel 0: W[e][n] (256x256 fp32) -> WT[n][e] f16.  grid 48 x 256 thr.
// ---------------------------------------------------------------------------
__global__ __launch_bounds__(256) void prep_w(
    const float* __restrict__ Wq, const float* __restrict__ Wk,
    const float* __restrict__ Wv, __fp16* __restrict__ WT) {
  int bi = blockIdx.x;
  int mat = bi >> 4, ngrp = bi & 15;
  const float* src = (mat == 0) ? Wq : (mat == 1) ? Wk : Wv;
  __fp16* dst = WT + mat * (EMB * EMB);
  int n = ngrp * 16 + (threadIdx.x >> 4);
  int e0 = (threadIdx.x & 15) * 16;
  H8 v0, v1;
#pragma unroll
  for (int j = 0; j < 8; ++j) v0.e[j] = (__fp16)src[(e0 + j) * EMB + n];
#pragma unroll
  for (int j = 0; j < 8; ++j) v1.e[j] = (__fp16)src[(e0 + 8 + j) * EMB + n];
  *(half8v*)(dst + n * EMB + e0) = v0.v;
  *(half8v*)(dst + n * EMB + e0 + 8) = v1.v;
}

// ---------------------------------------------------------------------------
// Kernel 1: projections (f16 MFMA). Wave converts 16 X-rows to f16 once,
// reuses across 4 heads. 1536 waves -> 384 blocks x 256 thr.
//   mat 0: Q[b,h,r,s]; mat 1: K[b,h,c,s]; mat 2: VT[b,h,s,c].
// ---------------------------------------------------------------------------
__global__ __launch_bounds__(256) void proj_kernel(
    const float* __restrict__ rowe, const float* __restrict__ cole,
    const __fp16* __restrict__ WT,
    __fp16* __restrict__ Q, __fp16* __restrict__ K,
    __fp16* __restrict__ VT) {
  int tid = threadIdx.x;
  int wid = tid >> 6, lane = tid & 63, l15 = lane & 15, quad = lane >> 4;
  int wt = blockIdx.x * 4 + wid;        // 0..1535
  int mat = wt >> 9;                    // 0=Q 1=K 2=V
  int t = wt & 511;
  int rt = t >> 2, ng = t & 3;          // rt 0..127, head group 0..3
  const float* X = (mat == 0) ? rowe : cole;
  const __fp16* Wm = WT + mat * (EMB * EMB);
  const float* xrow = X + (size_t)(rt * 16 + l15) * EMB + quad * 8;

  half8v xf[8];
#pragma unroll
  for (int e = 0; e < 8; ++e) {
    f32x4 b0 = *(const f32x4*)(xrow + e * 32);
    f32x4 b1 = *(const f32x4*)(xrow + e * 32 + 4);
    H8 x;
    x.h[0] = __builtin_amdgcn_cvt_pkrtz(b0[0], b0[1]);
    x.h[1] = __builtin_amdgcn_cvt_pkrtz(b0[2], b0[3]);
    x.h[2] = __builtin_amdgcn_cvt_pkrtz(b1[0], b1[1]);
    x.h[3] = __builtin_amdgcn_cvt_pkrtz(b1[2], b1[3]);
    xf[e] = x.v;
  }
  int row = rt * 16 + l15;
  int b = row >> 9, loc = row & 511;
#pragma unroll
  for (int hh = 0; hh < 4; ++hh) {
    int nt = ng * 4 + hh;
    const half8v* ap = (const half8v*)(Wm + (nt * 16 + l15) * EMB + quad * 8);
    f32x4 acc = {0.f, 0.f, 0.f, 0.f};
#pragma unroll
    for (int e = 0; e < 8; ++e)
      acc = __builtin_amdgcn_mfma_f32_16x16x32_f16(ap[e * 4], xf[e], acc, 0, 0, 0);
    if (mat < 2) {
      H4 pk;
      pk.h[0] = __builtin_amdgcn_cvt_pkrtz(acc[0], acc[1]);
      pk.h[1] = __builtin_amdgcn_cvt_pkrtz(acc[2], acc[3]);
      __fp16* dst = ((mat == 0) ? Q : K) +
          ((size_t)((b * NH + nt) * 512 + loc) * SD + quad * 4);
      *(half4v*)dst = pk.v;
    } else {
#pragma unroll
      for (int i = 0; i < 4; ++i)
        VT[(size_t)((b * NH + nt) * SD + quad * 4 + i) * CC + loc] = (__fp16)acc[i];
    }
  }
}

// ---------------------------------------------------------------------------
// Kernel 2: fused mixed-score attention, c-split flash, f16 packed MLP.
// grid (16 rb, 16 h, 4 b) x 256 thr. Block = 2 row-tiles x 2 c-halves.
// Phase 1: MFMA S^T -> packed-f16 MLP (v_pk_fma_f16 / v_pk_max_f16 /
//          v_dot2_f32_f16, m-pairs) -> f16 scores to swizzled LDS.
// Phase 2: exp2 + l + P.V f16 MFMA. Halves merged flash-style, 1 barrier.
// ---------------------------------------------------------------------------
__global__ __launch_bounds__(256) void attn_kernel(
    const __fp16* __restrict__ Q, const __fp16* __restrict__ K,
    const __fp16* __restrict__ VT, const float* __restrict__ cost,
    const float* __restrict__ m1w, const float* __restrict__ m1b,
    const float* __restrict__ m2w, const float* __restrict__ m2b,
    float* __restrict__ out) {
  __shared__ alignas(16) __fp16 Psh[4][16 * 256];     // 32 KB
  __shared__ float Osh[2][256];                        // ch==1 partial O
  __shared__ float MLsh[2][2][2][16];                  // [rt][ch][m|l][row]
  int tid = threadIdx.x;
  int wid = tid >> 6, lane = tid & 63, l15 = lane & 15, quad = lane >> 4;
  int rt = wid >> 1, ch = wid & 1;
  int rb = blockIdx.x, h = blockIdx.y, b = blockIdx.z;
  int bh = b * NH + h;
  int r0 = rb * 32 + rt * 16;
  int cbase = ch * 256;

  // per-head MLP weights, m-pairs packed into half2 (RTE casts, off hot path)
  half2v wa2[8], wc2[8], wd2[8], we2[8];
#pragma unroll
  for (int mp = 0; mp < 8; ++mp) {
    wa2[mp] = half2v{(__fp16)(m1w[(h * 2 + 0) * MH + 2 * mp] * 0.25f),
                     (__fp16)(m1w[(h * 2 + 0) * MH + 2 * mp + 1] * 0.25f)};
    wc2[mp] = half2v{(__fp16)m1w[(h * 2 + 1) * MH + 2 * mp],
                     (__fp16)m1w[(h * 2 + 1) * MH + 2 * mp + 1]};
    wd2[mp] = half2v{(__fp16)m1b[h * MH + 2 * mp],
                     (__fp16)m1b[h * MH + 2 * mp + 1]};
    we2[mp] = half2v{(__fp16)m2w[h * MH + 2 * mp],
                     (__fp16)m2w[h * MH + 2 * mp + 1]};
  }
  float wb2 = m2b[h];
  const half2v hz2 = {(__fp16)0.f, (__fp16)0.f};

  // loop-invariant Q fragment (B-operand): zero for k>=16 -> kills junk K k>=16
  half8v qf = {0, 0, 0, 0, 0, 0, 0, 0};
  const __fp16* Qb = Q + (size_t)bh * RR * SD;
  if (quad < 2) qf = *(const half8v*)(Qb + (r0 + l15) * SD + quad * 8);

  const __fp16* Kb = K + ((size_t)bh * CC + cbase) * SD;
  const float* crow = cost + ((size_t)b * RR + r0 + l15) * CC + cbase;
  __fp16* psrow = &Psh[wid][l15 * 256];

  // ---- phase 1: scores + packed MLP + per-row max (prefetched) ----
  float mrun = -1e30f;
  half8v kf_c = *(const half8v*)(Kb + l15 * SD + quad * 8);  // junk k>=16 ok
  f32x4 cf_c = *(const f32x4*)(crow + quad * 4);
#pragma unroll 4
  for (int it = 0; it < 16; ++it) {
    int itn = (it + 1) & 15;                   // wrap: unused on last iter
    half8v kf_n = *(const half8v*)(Kb + (itn * 16 + l15) * SD + quad * 8);
    f32x4 cf_n = *(const f32x4*)(crow + itn * 16 + quad * 4);

    f32x4 acc = {0.f, 0.f, 0.f, 0.f};
    acc = __builtin_amdgcn_mfma_f32_16x16x32_f16(kf_c, qf, acc, 0, 0, 0);
    // lane: r = r0+l15 (fixed), local c = it*16 + 4*quad + i
    int c0 = it * 16 + quad * 4;
    float sv[4];
#pragma unroll
    for (int i = 0; i < 4; ++i) {
      half2v x2 = __builtin_amdgcn_cvt_pkrtz(acc[i], acc[i]);
      half2v c2 = __builtin_amdgcn_cvt_pkrtz(cf_c[i], cf_c[i]);
      float s = wb2;
#pragma unroll
      for (int mp = 0; mp < 8; ++mp) {
        half2v t1 = __builtin_elementwise_fma(wc2[mp], c2, wd2[mp]);
        t1 = __builtin_elementwise_fma(wa2[mp], x2, t1);
        t1 = __builtin_elementwise_max(t1, hz2);
        s = __builtin_amdgcn_fdot2(we2[mp], t1, s, false);
      }
      sv[i] = s;
      mrun = fmaxf(mrun, s);
    }
    H4 pk;
    pk.h[0] = __builtin_amdgcn_cvt_pkrtz(sv[0], sv[1]);
    pk.h[1] = __builtin_amdgcn_cvt_pkrtz(sv[2], sv[3]);
    int g = ((c0 >> 3) ^ (l15 & 7));          // 16B-granule XOR swizzle
    *(half4v*)(psrow + g * 8 + (c0 & 7)) = pk.v;
    kf_c = kf_n; cf_c = cf_n;
  }
  mrun = fmaxf(mrun, __shfl_xor(mrun, 16));
  mrun = fmaxf(mrun, __shfl_xor(mrun, 32));   // per-row (l15) max

  // ---- phase 2: exp + l-sum + P·V (prefetched) ----
  const __fp16* vb = VT + ((size_t)bh * SD + l15) * CC + cbase;
  f32x4 o = {0.f, 0.f, 0.f, 0.f};
  float lsum = 0.f;
  const float L2E = 1.44269504088896f;
  float mb2 = mrun * L2E;
  half8v vf_c = *(const half8v*)(vb + quad * 8);
  int g0 = ((quad * 8) >> 3) ^ (l15 & 7);
  H8 pr_c; pr_c.v = *(const half8v*)(psrow + g0 * 8);
#pragma unroll
  for (int it = 0; it < 8; ++it) {
    int itn = (it + 1) & 7;
    half8v vf_n = *(const half8v*)(vb + itn * 32 + quad * 8);
    int c0n = itn * 32 + quad * 8;
    int gn = ((c0n >> 3) ^ (l15 & 7));
    H8 pr_n; pr_n.v = *(const half8v*)(psrow + gn * 8);
    float p[8];
#pragma unroll
    for (int j = 0; j < 8; ++j) {
      float x = (float)pr_c.e[j];
      p[j] = __builtin_amdgcn_exp2f(fmaf(x, L2E, -mb2));
      lsum += p[j];
    }
    H8 pf;
#pragma unroll
    for (int jj = 0; jj < 4; ++jj)
      pf.h[jj] = __builtin_amdgcn_cvt_pkrtz(p[2 * jj], p[2 * jj + 1]);
    o = __builtin_amdgcn_mfma_f32_16x16x32_f16(pf.v, vf_c, o, 0, 0, 0);
    vf_c = vf_n; pr_c = pr_n;
  }
  lsum += __shfl_xor(lsum, 16);
  lsum += __shfl_xor(lsum, 32);               // per-row (l15) partial l

  // ---- merge the two c-halves ----
  if (quad == 0) { MLsh[rt][ch][0][l15] = mrun; MLsh[rt][ch][1][l15] = lsum; }
  if (ch == 1) {
#pragma unroll
    for (int i = 0; i < 4; ++i) Osh[rt][(quad * 4 + i) * 16 + l15] = o[i];
  }
  __syncthreads();
  if (ch == 0) {
#pragma unroll
    for (int i = 0; i < 4; ++i) {
      int r = quad * 4 + i;
      float m0 = MLsh[rt][0][0][r], l0 = MLsh[rt][0][1][r];
      float m1 = MLsh[rt][1][0][r], l1 = MLsh[rt][1][1][r];
      float M = fmaxf(m0, m1);
      float a0 = __builtin_amdgcn_exp2f((m0 - M) * L2E);
      float a1 = __builtin_amdgcn_exp2f((m1 - M) * L2E);
      float l = a0 * l0 + a1 * l1;
      float val = (a0 * o[i] + a1 * Osh[rt][r * 16 + l15]) / l;
      out[((size_t)b * RR + r0 + r) * (NH * SD) + h * SD + l15] = val;
    }
  }
}

// ---------------------------------------------------------------------------
extern "C" void kernel_launch(void* const* d_in, const int* in_sizes, int n_in,
                              void* d_out, int out_size, void* d_ws, size_t ws_size,
                              hipStream_t stream) {
  const float* rowe = (const float*)d_in[0];
  const float* cole = (const float*)d_in[1];
  const float* cost = (const float*)d_in[2];
  const float* Wq   = (const float*)d_in[3];
  const float* Wk   = (const float*)d_in[4];
  const float* Wv   = (const float*)d_in[5];
  const float* m1w  = (const float*)d_in[6];
  const float* m1b  = (const float*)d_in[7];
  const float* m2w  = (const float*)d_in[8];
  const float* m2b  = (const float*)d_in[9];
  float* outp = (float*)d_out;

  // workspace layout (f16 elements):
  //   Q  [4,16,512,16]  @ 0        (524288)
  //   K  [4,16,512,16]  @ 524288   (524288)
  //   VT [4,16,16,512]  @ 1048576  (524288)
  //   WT [3,256,256]    @ 1572864  (196608)   -> 3538944 bytes total
  __fp16* ws = (__fp16*)d_ws;
  __fp16* Qw  = ws;
  __fp16* Kw  = ws + 524288;
  __fp16* VTw = ws + 1048576;
  __fp16* WTw = ws + 1572864;

  prep_w<<<dim3(48, 1, 1), 256, 0, stream>>>(Wq, Wk, Wv, WTw);
  proj_kernel<<<dim3(384, 1, 1), 256, 0, stream>>>(rowe, cole, WTw, Qw, Kw, VTw);
  attn_kernel<<<dim3(16, NH, NB), 256, 0, stream>>>(Qw, Kw, VTw, cost,
                                                    m1w, m1b, m2w, m2b, outp);
}